// Round 3
// baseline (70.873 us; speedup 1.0000x reference)
//
#include <hip/hip_runtime.h>
#include <hip/hip_bf16.h>

typedef __attribute__((ext_vector_type(4))) float  f32x4;
typedef __attribute__((ext_vector_type(8))) float  f32x8;
typedef __attribute__((ext_vector_type(8))) __bf16 bf16x8;

#define NR 4096
#define NC 256
#define DD 128
#define BR 64
#define BC 32
#define CURVC 1.0f

// 64 rows x 32 cols per block. X fp32 in LDS (32 f32x4 units/row, XOR-swizzled),
// P/A bf16 in LDS (16 bf16x8 units/row, XOR-swizzled). Pure VALU fp32 dots.
// OUTPUT IS FP32 (reference returns float32 — rounds 1/2 failed on dtype).
__global__ __launch_bounds__(256) void hyp_mlr_kernel(
    const float* __restrict__ Xg,        // output_before [4096][128]
    const float* __restrict__ Ag,        // a_mlr [256][128]
    const float* __restrict__ Pg,        // p_mlr [256][128]
    float* __restrict__ Out)             // [4096][256] fp32
{
    __shared__ f32x4  ldsX[BR * 32];     // 32 KB, unit index u ^ (row&7)
    __shared__ bf16x8 ldsP[BC * 16];     // 8 KB
    __shared__ bf16x8 ldsA[BC * 16];     // 8 KB
    __shared__ float  scrC[3][4][BC];    // p2, pa, a2 partials
    __shared__ float  scrR[2][BR];       // x2 halves
    __shared__ float  colP2[BC], colMPA[BC], colINA[BC], colNA[BC];
    __shared__ float  rowX2[BR];

    const int t    = threadIdx.x;
    const int row0 = blockIdx.x * BR;
    const int c0   = blockIdx.y * BC;

    // ---- stage X (fp32, swizzled f32x4 units) ----
    #pragma unroll
    for (int q = 0; q < 8; ++q) {
        int uid = q * 256 + t;
        int row = uid >> 5, u = uid & 31;
        ldsX[row * 32 + (u ^ (row & 7))] =
            *(const f32x4*)(Xg + (size_t)(row0 + row) * DD + u * 4);
    }
    // ---- stage P, A (bf16x8 units, swizzled) ----
    #pragma unroll
    for (int q = 0; q < 2; ++q) {
        int uid = q * 256 + t;
        int row = uid >> 4, u = uid & 15;
        f32x8 pf = *(const f32x8*)(Pg + (size_t)(c0 + row) * DD + u * 8);
        f32x8 af = *(const f32x8*)(Ag + (size_t)(c0 + row) * DD + u * 8);
        bf16x8 pv, av;
        #pragma unroll
        for (int e = 0; e < 8; ++e) { pv[e] = (__bf16)pf[e]; av[e] = (__bf16)af[e]; }
        ldsP[row * 16 + (u ^ (row & 7))] = pv;
        ldsA[row * 16 + (u ^ (row & 7))] = av;
    }
    __syncthreads();

    // ---- stats partials ----
    if (t < 128) {
        int c = t & 31, q = t >> 5;                 // q in 0..3, 32 elems each
        float sp2 = 0.f, spa = 0.f, sa2 = 0.f;
        #pragma unroll
        for (int uu = 0; uu < 4; ++uu) {
            int u = q * 4 + uu;
            bf16x8 pv = ldsP[c * 16 + (u ^ (c & 7))];
            bf16x8 av = ldsA[c * 16 + (u ^ (c & 7))];
            #pragma unroll
            for (int e = 0; e < 8; ++e) {
                float pe = (float)pv[e], ae = (float)av[e];
                sp2 += pe * pe; spa += pe * ae; sa2 += ae * ae;
            }
        }
        scrC[0][q][c] = sp2; scrC[1][q][c] = spa; scrC[2][q][c] = sa2;
    } else {
        int r = (t - 128) >> 1, h = t & 1;          // r in 0..63, 64 elems each
        float sx2 = 0.f;
        #pragma unroll
        for (int uu = 0; uu < 16; ++uu) {
            int u = h * 16 + uu;
            f32x4 xv = ldsX[r * 32 + (u ^ (r & 7))];
            sx2 += xv[0]*xv[0] + xv[1]*xv[1] + xv[2]*xv[2] + xv[3]*xv[3];
        }
        scrR[h][r] = sx2;
    }
    __syncthreads();

    // ---- stats combine ----
    if (t < 32) {
        float p2 = scrC[0][0][t] + scrC[0][1][t] + scrC[0][2][t] + scrC[0][3][t];
        float pa = scrC[1][0][t] + scrC[1][1][t] + scrC[1][2][t] + scrC[1][3][t];
        float a2 = scrC[2][0][t] + scrC[2][1][t] + scrC[2][2][t] + scrC[2][3][t];
        float na  = sqrtf(a2);
        float ina = 1.0f / fmaxf(na, 1e-12f);
        colP2[t] = p2; colNA[t] = na; colINA[t] = ina;
        colMPA[t] = -pa * ina;                      // dot(mp, a_hat)
    } else if (t >= 32 && t < 96) {
        int r = t - 32;
        rowX2[r] = scrR[0][r] + scrR[1][r];
    }
    __syncthreads();

    // ---- main loop: dual dots, 4 rows x 2 cols per thread ----
    const int rb = t & 15;       // rows rb, rb+16, rb+32, rb+48
    const int cb = t >> 4;       // cols cb, cb+16
    float accP[4][2] = {{0.f,0.f},{0.f,0.f},{0.f,0.f},{0.f,0.f}};
    float accA[4][2] = {{0.f,0.f},{0.f,0.f},{0.f,0.f},{0.f,0.f}};

    for (int kc = 0; kc < 16; ++kc) {               // 8 elems per chunk
        float xv[4][8];
        #pragma unroll
        for (int i = 0; i < 4; ++i) {
            int r = rb + 16 * i;
            f32x4 x0 = ldsX[r * 32 + ((2 * kc)     ^ (r & 7))];
            f32x4 x1 = ldsX[r * 32 + ((2 * kc + 1) ^ (r & 7))];
            xv[i][0] = x0[0]; xv[i][1] = x0[1]; xv[i][2] = x0[2]; xv[i][3] = x0[3];
            xv[i][4] = x1[0]; xv[i][5] = x1[1]; xv[i][6] = x1[2]; xv[i][7] = x1[3];
        }
        float pv[2][8], av[2][8];
        #pragma unroll
        for (int j = 0; j < 2; ++j) {
            int c = cb + 16 * j;
            bf16x8 p8 = ldsP[c * 16 + (kc ^ (c & 7))];
            bf16x8 a8 = ldsA[c * 16 + (kc ^ (c & 7))];
            #pragma unroll
            for (int e = 0; e < 8; ++e) { pv[j][e] = (float)p8[e]; av[j][e] = (float)a8[e]; }
        }
        #pragma unroll
        for (int i = 0; i < 4; ++i)
            #pragma unroll
            for (int j = 0; j < 2; ++j)
                #pragma unroll
                for (int e = 0; e < 8; ++e) {
                    accP[i][j] += xv[i][e] * pv[j][e];
                    accA[i][j] += xv[i][e] * av[j][e];
                }
    }

    // ---- epilogue (fp32 stores) ----
    #pragma unroll
    for (int i = 0; i < 4; ++i) {
        int   r  = rb + 16 * i;
        float x2 = rowX2[r];
        #pragma unroll
        for (int j = 0; j < 2; ++j) {
            int   c   = cb + 16 * j;
            float xy  = -accP[i][j];                          // dot(mp, x)
            float xa  = accA[i][j] * colINA[c];               // dot(x, a_hat)
            float p2  = colP2[c];
            float A1  = 1.f + 2.f * CURVC * xy + CURVC * x2;
            float B1  = 1.f - CURVC * p2;
            float den = 1.f + 2.f * CURVC * xy + CURVC * CURVC * p2 * x2;
            float idn = 1.f / den;
            float r2  = (A1 * A1 * p2 + 2.f * A1 * B1 * xy + B1 * B1 * x2) * idn * idn;
            float lam = 2.f / (1.f - r2);
            float z   = (A1 * colMPA[c] + B1 * xa) * idn * lam;
            float az  = fabsf(z);
            float as  = logf(az + sqrtf(az * az + 1.f));      // asinh(|z|)
            float o   = 2.f * colNA[c] * copysignf(as, z);
            Out[(size_t)(row0 + r) * NC + (c0 + c)] = o;
        }
    }
}

extern "C" void kernel_launch(void* const* d_in, const int* in_sizes, int n_in,
                              void* d_out, int out_size, void* d_ws, size_t ws_size,
                              hipStream_t stream) {
    const float* X = (const float*)d_in[0];   // output_before
    const float* A = (const float*)d_in[1];   // a_mlr
    const float* P = (const float*)d_in[2];   // p_mlr
    float* out = (float*)d_out;
    dim3 grid(NR / BR, NC / BC);
    hipLaunchKernelGGL(hyp_mlr_kernel, grid, dim3(256), 0, stream, X, A, P, out);
}

// Round 5
// 63.665 us; speedup vs baseline: 1.1132x; 1.1132x over previous
//
#include <hip/hip_runtime.h>
#include <hip/hip_bf16.h>

typedef __attribute__((ext_vector_type(4))) float  f32x4;
typedef __attribute__((ext_vector_type(8))) float  f32x8;
typedef __attribute__((ext_vector_type(8))) __bf16 bf16x8;
typedef __attribute__((ext_vector_type(4))) __bf16 bf16x4;

#define NR 4096
#define NC 256
#define DD 128
#define BR 64
#define BC 32
#define CURVC 1.0f

// 64 rows x 32 cols per block, grid (64,8) = 512 blocks (2/CU).
// X/P/A staged bf16 in LDS, 16B units XOR-swizzled (u ^ (row&7)).
// Stats computed fp32-exact during staging (16-lane shfl_xor reduce).
// Dots via mfma_f32_16x16x32_bf16; A/B frag: elems0-3 k=4*hi+e, elems4-7 k=16+4*hi+e.
// C/D frag (m89-verified): col=lane&15, row=4*(lane>>4)+reg.
__global__ __launch_bounds__(256) void hyp_mlr_kernel(
    const float* __restrict__ Xg,        // output_before [4096][128]
    const float* __restrict__ Ag,        // a_mlr [256][128]
    const float* __restrict__ Pg,        // p_mlr [256][128]
    float* __restrict__ Out)             // [4096][256] fp32
{
    __shared__ bf16x8 ldsX[BR * 16];     // 16 KB
    __shared__ bf16x8 ldsP[BC * 16];     // 8 KB
    __shared__ bf16x8 ldsA[BC * 16];     // 8 KB
    __shared__ float  rowX2[BR];
    __shared__ float  colP2[BC], colMPA[BC], colINA[BC], colNA[BC];

    const int t    = threadIdx.x;
    const int row0 = blockIdx.x * BR;
    const int c0   = blockIdx.y * BC;

    // ---- stage X (bf16) + fp32-exact row x2 ----
    #pragma unroll
    for (int q = 0; q < 4; ++q) {
        int uid = q * 256 + t;
        int row = uid >> 4, u = uid & 15;      // 16 consecutive lanes share a row
        f32x8 xf = *(const f32x8*)(Xg + (size_t)(row0 + row) * DD + u * 8);
        bf16x8 xv;
        float s = 0.f;
        #pragma unroll
        for (int e = 0; e < 8; ++e) { xv[e] = (__bf16)xf[e]; s += xf[e] * xf[e]; }
        ldsX[row * 16 + (u ^ (row & 7))] = xv;
        #pragma unroll
        for (int m = 1; m < 16; m <<= 1) s += __shfl_xor(s, m);
        if ((t & 15) == 0) rowX2[row] = s;
    }
    // ---- stage P, A (bf16) + fp32-exact col stats ----
    #pragma unroll
    for (int q = 0; q < 2; ++q) {
        int uid = q * 256 + t;
        int col = uid >> 4, u = uid & 15;
        f32x8 pf = *(const f32x8*)(Pg + (size_t)(c0 + col) * DD + u * 8);
        f32x8 af = *(const f32x8*)(Ag + (size_t)(c0 + col) * DD + u * 8);
        bf16x8 pv, av;
        float sp2 = 0.f, spa = 0.f, sa2 = 0.f;
        #pragma unroll
        for (int e = 0; e < 8; ++e) {
            float pe = pf[e], ae = af[e];
            pv[e] = (__bf16)pe; av[e] = (__bf16)ae;
            sp2 += pe * pe; spa += pe * ae; sa2 += ae * ae;
        }
        ldsP[col * 16 + (u ^ (col & 7))] = pv;
        ldsA[col * 16 + (u ^ (col & 7))] = av;
        #pragma unroll
        for (int m = 1; m < 16; m <<= 1) {
            sp2 += __shfl_xor(sp2, m);
            spa += __shfl_xor(spa, m);
            sa2 += __shfl_xor(sa2, m);
        }
        if ((t & 15) == 0) {
            float na  = sqrtf(sa2);
            float ina = 1.f / fmaxf(na, 1e-12f);
            colP2[col] = sp2; colNA[col] = na; colINA[col] = ina;
            colMPA[col] = -spa * ina;            // dot(mp, a_hat)
        }
    }
    __syncthreads();

    // ---- MFMA: XP^T and XA^T, 16x16x32 bf16, wave w -> rows 16w..16w+15 ----
    const int l  = t & 63, w = t >> 6;
    const int lo = l & 15, hi = l >> 4;
    const __bf16* xb = (const __bf16*)ldsX;
    const __bf16* pb = (const __bf16*)ldsP;
    const __bf16* ab = (const __bf16*)ldsA;

    const int xrow = 16 * w + lo;
    const int xsw  = xrow & 7;
    const int hsel = 4 * (hi & 1);     // bf16-elem offset within 16B unit
    const int uq   = hi >> 1;

    f32x4 zv = {0.f, 0.f, 0.f, 0.f};
    f32x4 accP[2] = {zv, zv};
    f32x4 accA[2] = {zv, zv};

    #pragma unroll
    for (int kk = 0; kk < 4; ++kk) {
        int u0 = 4 * kk + uq;
        bf16x4 h0 = *(const bf16x4*)(xb + xrow * 128 + ((u0    ) ^ xsw) * 8 + hsel);
        bf16x4 h1 = *(const bf16x4*)(xb + xrow * 128 + ((u0 + 2) ^ xsw) * 8 + hsel);
        bf16x8 xf;
        xf[0]=h0[0]; xf[1]=h0[1]; xf[2]=h0[2]; xf[3]=h0[3];
        xf[4]=h1[0]; xf[5]=h1[1]; xf[6]=h1[2]; xf[7]=h1[3];
        #pragma unroll
        for (int j = 0; j < 2; ++j) {
            int pc = 16 * j + lo, sw = pc & 7;
            bf16x4 p0 = *(const bf16x4*)(pb + pc * 128 + ((u0    ) ^ sw) * 8 + hsel);
            bf16x4 p1 = *(const bf16x4*)(pb + pc * 128 + ((u0 + 2) ^ sw) * 8 + hsel);
            bf16x4 a0 = *(const bf16x4*)(ab + pc * 128 + ((u0    ) ^ sw) * 8 + hsel);
            bf16x4 a1 = *(const bf16x4*)(ab + pc * 128 + ((u0 + 2) ^ sw) * 8 + hsel);
            bf16x8 pfr, afr;
            pfr[0]=p0[0]; pfr[1]=p0[1]; pfr[2]=p0[2]; pfr[3]=p0[3];
            pfr[4]=p1[0]; pfr[5]=p1[1]; pfr[6]=p1[2]; pfr[7]=p1[3];
            afr[0]=a0[0]; afr[1]=a0[1]; afr[2]=a0[2]; afr[3]=a0[3];
            afr[4]=a1[0]; afr[5]=a1[1]; afr[6]=a1[2]; afr[7]=a1[3];
            accP[j] = __builtin_amdgcn_mfma_f32_16x16x32_bf16(xf, pfr, accP[j], 0, 0, 0);
            accA[j] = __builtin_amdgcn_mfma_f32_16x16x32_bf16(xf, afr, accA[j], 0, 0, 0);
        }
    }

    // ---- epilogue (fp32 stores) ----
    #pragma unroll
    for (int r = 0; r < 4; ++r) {
        int   rr = 16 * w + 4 * hi + r;
        float x2 = rowX2[rr];
        #pragma unroll
        for (int j = 0; j < 2; ++j) {
            int   c   = 16 * j + lo;
            float xy  = -accP[j][r];                          // dot(mp, x)
            float xa  = accA[j][r] * colINA[c];               // dot(x, a_hat)
            float p2  = colP2[c];
            float A1  = 1.f + 2.f * CURVC * xy + CURVC * x2;
            float B1  = 1.f - CURVC * p2;
            float den = 1.f + 2.f * CURVC * xy + CURVC * CURVC * p2 * x2;
            float idn = 1.f / den;
            float r2  = (A1 * A1 * p2 + 2.f * A1 * B1 * xy + B1 * B1 * x2) * idn * idn;
            float lam = 2.f / (1.f - r2);
            float z   = (A1 * colMPA[c] + B1 * xa) * idn * lam;
            float az  = fabsf(z);
            float as  = __logf(az + sqrtf(az * az + 1.f));    // asinh(|z|)
            float o   = 2.f * colNA[c] * copysignf(as, z);
            Out[(size_t)(row0 + rr) * NC + (c0 + c)] = o;
        }
    }
}

extern "C" void kernel_launch(void* const* d_in, const int* in_sizes, int n_in,
                              void* d_out, int out_size, void* d_ws, size_t ws_size,
                              hipStream_t stream) {
    const float* X = (const float*)d_in[0];   // output_before
    const float* A = (const float*)d_in[1];   // a_mlr
    const float* P = (const float*)d_in[2];   // p_mlr
    float* out = (float*)d_out;
    dim3 grid(NR / BR, NC / BC);
    hipLaunchKernelGGL(hyp_mlr_kernel, grid, dim3(256), 0, stream, X, A, P, out);
}